// Round 1
// baseline (33.784 us; speedup 1.0000x reference)
//
#include <hip/hip_runtime.h>
#include <hip/hip_bf16.h>

// TT embedding: vocab 65536 = 32*32*32*2 (+d-split), dim 1024.
// Cores: c0 (1,32,16), c1 (16,32,16), c2 (16,32,16), c3 (16,32,16), c4 (16,64,1).
// out[v,d] = sum_{r1..r4} c0[0,i0,r1] c1[r1,i1,r2] c2[r2,i2,r3] c3[r3,i3,r4] c4[r4,i4,0]
//   i0=v>>11, i1=(v>>6)&31, i2=(v>>1)&31, i3=(v&1)*16+(d>>6), i4=d&63

__global__ __launch_bounds__(256) void tt_embed_kernel(
    const float* __restrict__ c0,   // 32*16
    const float* __restrict__ c1,   // 16*32*16
    const float* __restrict__ c2,   // 16*32*16
    const float* __restrict__ c3,   // 16*32*16
    const float* __restrict__ c4,   // 16*64
    const int*   __restrict__ idx,  // 16384
    float*       __restrict__ out)  // 16384 x 1024
{
    const int token = blockIdx.x;
    const int t = threadIdx.x;
    const int v = idx[token];

    const int i0 = (v >> 11) & 31;
    const int i1 = (v >> 6) & 31;
    const int i2 = (v >> 1) & 31;
    const int vlow = v & 1;

    __shared__ float w2[16];
    __shared__ float w3[16];
    __shared__ float w4[16][17];   // [d1][r4], padded

    // Stage 1: w2[r2] = sum_r1 c0[i0,r1] * c1[r1,i1,r2]   (threads 0..15)
    if (t < 16) {
        float acc = 0.f;
        #pragma unroll
        for (int r1 = 0; r1 < 16; ++r1)
            acc += c0[i0 * 16 + r1] * c1[(r1 * 32 + i1) * 16 + t];
        w2[t] = acc;
    }
    __syncthreads();

    // Stage 2: w3[r3] = sum_r2 w2[r2] * c2[r2,i2,r3]   (threads 0..15)
    if (t < 16) {
        float acc = 0.f;
        #pragma unroll
        for (int r2 = 0; r2 < 16; ++r2)
            acc += w2[r2] * c2[(r2 * 32 + i2) * 16 + t];
        w3[t] = acc;
    }
    __syncthreads();

    // Stage 3: w4[d1][r4] = sum_r3 w3[r3] * c3[r3, vlow*16+d1, r4]  (all 256)
    {
        const int d1 = t >> 4;
        const int r4 = t & 15;
        const int i3 = vlow * 16 + d1;
        float acc = 0.f;
        #pragma unroll
        for (int r3 = 0; r3 < 16; ++r3)
            acc += w3[r3] * c3[(r3 * 32 + i3) * 16 + r4];
        w4[d1][r4] = acc;
    }
    __syncthreads();

    // Stage 4: out[d] = sum_r4 w4[d>>6][r4] * c4[r4, d&63]
    const int i4 = t & 63;
    float c4reg[16];
    #pragma unroll
    for (int r4 = 0; r4 < 16; ++r4)
        c4reg[r4] = c4[r4 * 64 + i4];

    float* outp = out + (size_t)token * 1024;
    #pragma unroll
    for (int k = 0; k < 4; ++k) {
        const int d = t + k * 256;
        const int d1 = d >> 6;
        float acc = 0.f;
        #pragma unroll
        for (int r4 = 0; r4 < 16; ++r4)
            acc += w4[d1][r4] * c4reg[r4];
        outp[d] = acc;
    }
}

extern "C" void kernel_launch(void* const* d_in, const int* in_sizes, int n_in,
                              void* d_out, int out_size, void* d_ws, size_t ws_size,
                              hipStream_t stream) {
    const float* c0  = (const float*)d_in[0];
    const float* c1  = (const float*)d_in[1];
    const float* c2  = (const float*)d_in[2];
    const float* c3  = (const float*)d_in[3];
    const float* c4  = (const float*)d_in[4];
    const int*   idx = (const int*)d_in[5];
    float* out = (float*)d_out;

    const int n_tokens = in_sizes[5];         // 8 * 2048 = 16384
    tt_embed_kernel<<<n_tokens, 256, 0, stream>>>(c0, c1, c2, c3, c4, idx, out);
}